// Round 1
// 366.635 us; speedup vs baseline: 2.2589x; 2.2589x over previous
//
#include <hip/hip_runtime.h>

#define EPS 1e-5f

typedef __bf16 bf16x8 __attribute__((ext_vector_type(8)));
typedef __bf16 bf16x4 __attribute__((ext_vector_type(4)));
typedef float f32x4 __attribute__((ext_vector_type(4)));

static __device__ __forceinline__ unsigned int f2bf(float f) {
    unsigned int u = __builtin_bit_cast(unsigned int, f);
    u = (u + 0x7fffu + ((u >> 16) & 1u)) >> 16;
    return u;
}

// async global->LDS, 16B per lane. LDS dest must be wave-uniform base (+lane*16 by HW).
// AS3 pointer = low 32 bits of generic LDS pointer (4GiB-aligned aperture).
static __device__ __forceinline__ void gll16(const void* g, void* l) {
    __builtin_amdgcn_global_load_lds(
        (const __attribute__((address_space(1))) unsigned int*)(unsigned long long)g,
        (__attribute__((address_space(3))) unsigned int*)(unsigned int)(unsigned long long)l,
        16, 0, 0);
}

// ---- pass 1: colsum partials (+ optional bf16 copy of x) ----
template <int XBF>
__global__ __launch_bounds__(256) void k_prep(const float* __restrict__ x,
                                              float* __restrict__ xs_part,
                                              unsigned short* __restrict__ xbf) {
    const int b = blockIdx.y, sc = blockIdx.x, tid = threadIdx.x;
    const size_t rowbase = ((size_t)(b * 4096 + sc * 128)) * 1024;
    const float4* src = (const float4*)(x + rowbase) + tid;
    uint2* dst = XBF ? ((uint2*)(xbf + rowbase) + tid) : (uint2*)0;
    float ax = 0.f, ay = 0.f, az = 0.f, aw = 0.f;
    for (int r = 0; r < 128; ++r) {
        float4 v = src[r * 256];
        ax += v.x; ay += v.y; az += v.z; aw += v.w;
        if (XBF) {
            uint2 p;
            p.x = f2bf(v.x) | (f2bf(v.y) << 16);
            p.y = f2bf(v.z) | (f2bf(v.w) << 16);
            dst[r * 256] = p;
        }
    }
    float4 o; o.x = ax; o.y = ay; o.z = az; o.w = aw;
    ((float4*)(xs_part + ((size_t)(b * 32 + sc)) * 1024))[tid] = o;
}

// ---- xs[b][j] = sum over 32 partials ----
__global__ void k_xsred(const float* __restrict__ xs_part, float* __restrict__ xs) {
    const int b = blockIdx.y, j = blockIdx.x * 256 + threadIdx.x;
    const float* p = xs_part + (size_t)b * 32 * 1024 + j;
    float s = 0.f;
#pragma unroll
    for (int sc = 0; sc < 32; ++sc) s += p[sc * 1024];
    xs[b * 1024 + j] = s;
}

// ---- convert B (f32 [1024][1024]) -> bf16 ----
__global__ void k_bconv(const float* __restrict__ B, unsigned short* __restrict__ Bb) {
    const int i = blockIdx.x * 256 + threadIdx.x;
    float4 v = ((const float4*)B)[i];
    uint2 p;
    p.x = f2bf(v.x) | (f2bf(v.y) << 16);
    p.y = f2bf(v.z) | (f2bf(v.w) << 16);
    ((uint2*)Bb)[i] = p;
}

// ---- query[b,i] = dot(A[i,:], xs[b,:]) ----
__global__ void k_query(const float* __restrict__ A, const float* __restrict__ xs,
                        float* __restrict__ q) {
    const int b = blockIdx.y;
    const int i = blockIdx.x * 256 + threadIdx.x;
    const float4* ar = (const float4*)(A + (size_t)i * 1024);
    const float4* xr = (const float4*)(xs + b * 1024);
    float acc = 0.f;
    for (int k = 0; k < 256; ++k) {
        float4 a = ar[k], v = xr[k];
        acc += a.x * v.x + a.y * v.y + a.z * v.z + a.w * v.w;
    }
    q[b * 1024 + i] = acc;
}

// ---- normalize query rows in place ----
__global__ void k_qnorm(float* q) {
    const int b = blockIdx.x, tid = threadIdx.x;
    float4* qp = (float4*)(q + (size_t)b * 1024);
    float4 v = qp[tid];
    float ss = v.x * v.x + v.y * v.y + v.z * v.z + v.w * v.w;
    for (int o = 1; o < 64; o <<= 1) ss += __shfl_xor(ss, o);
    __shared__ float wsum[4];
    if ((tid & 63) == 0) wsum[tid >> 6] = ss;
    __syncthreads();
    float inv = 1.f / (EPS + sqrtf(wsum[0] + wsum[1] + wsum[2] + wsum[3]));
    v.x *= inv; v.y *= inv; v.z *= inv; v.w *= inv;
    qp[tid] = v;
}

// ---- w[b,j] = sum_i B[i,j] * qhat[b,i] ----
__global__ void k_w(const float* __restrict__ B, const float* __restrict__ q,
                    float* __restrict__ w) {
    const int b = blockIdx.y;
    const int j = blockIdx.x * 256 + threadIdx.x;
    const float* qb = q + (size_t)b * 1024;
    float acc = 0.f;
    for (int i = 0; i < 1024; ++i) acc += B[(size_t)i * 1024 + j] * qb[i];
    w[b * 1024 + j] = acc;
}

// ---- pass 3: nsq[token] partials via LDS-staged MFMA GEMM ----
// grid (512 token-tiles, 2 m-halves); tile = 128 tokens x 512 m, K=1024.
template <int XBF>
__global__ __launch_bounds__(256, 2) void k_nsq(const float* __restrict__ x,
                                                const unsigned short* __restrict__ xbf,
                                                const unsigned short* __restrict__ Bb,
                                                float* __restrict__ nsq_g) {
    __shared__ unsigned short Xs[128 * 64];  // 16 KB, XOR-swizzled (chunk16 ^= row&7)
    __shared__ unsigned short Bs[128 * 64];  // 16 KB, same swizzle
    __shared__ float nsq_s[128];

    const int tid = threadIdx.x;
    const int lane = tid & 63;
    const int l15 = lane & 15, lg = lane >> 4;
    const int w = tid >> 6;
    const int wr = w >> 1, wc = w & 1;       // waves 2x2 over 128x128 sub-tile
    const int st = blockIdx.x * 128;         // global token base (4096%128==0: no batch crossing)
    const int mh = blockIdx.y;               // m-half

    float nsq_reg[4][4];
#pragma unroll
    for (int mi = 0; mi < 4; ++mi)
#pragma unroll
        for (int r = 0; r < 4; ++r) nsq_reg[mi][r] = 0.f;

    for (int mti = 0; mti < 4; ++mti) {
        const int mt = mh * 4 + mti;
        f32x4 acc[4][4];
#pragma unroll
        for (int mi = 0; mi < 4; ++mi)
#pragma unroll
            for (int ni = 0; ni < 4; ++ni) acc[mi][ni] = (f32x4){0.f, 0.f, 0.f, 0.f};

        for (int ks = 0; ks < 16; ++ks) {
            __syncthreads();  // prev compute done; LDS reusable
            if (XBF) {
#pragma unroll
                for (int it = 0; it < 4; ++it) {
                    const int idx = it * 256 + tid;
                    const int row = idx >> 3, c = idx & 7;
                    const int csw = (c ^ (row & 7)) * 8;  // pre-swizzled source chunk
                    char* base = (char*)Xs + (size_t)(it * 256 + (tid & ~63)) * 16;
                    gll16(xbf + (size_t)(st + row) * 1024 + ks * 64 + csw, base);
                    char* baseB = (char*)Bs + (size_t)(it * 256 + (tid & ~63)) * 16;
                    gll16(Bb + (size_t)(mt * 128 + row) * 1024 + ks * 64 + csw, baseB);
                }
            } else {
                // reg-stage X from f32 + convert, swizzled ds_write
                const int row = tid >> 1, kh = tid & 1;
                const float* srcx = x + (size_t)(st + row) * 1024 + ks * 64 + kh * 32;
                char* ldsrow = (char*)Xs + row * 128;
                const int sw = (row & 7) << 4;
#pragma unroll
                for (int j = 0; j < 4; ++j) {
                    float4 v0 = ((const float4*)srcx)[j * 2];
                    float4 v1 = ((const float4*)srcx)[j * 2 + 1];
                    uint4 p;
                    p.x = f2bf(v0.x) | (f2bf(v0.y) << 16);
                    p.y = f2bf(v0.z) | (f2bf(v0.w) << 16);
                    p.z = f2bf(v1.x) | (f2bf(v1.y) << 16);
                    p.w = f2bf(v1.z) | (f2bf(v1.w) << 16);
                    *(uint4*)(ldsrow + (((kh * 4 + j) * 16) ^ sw)) = p;
                }
#pragma unroll
                for (int it = 0; it < 4; ++it) {
                    const int idx = it * 256 + tid;
                    const int brow = idx >> 3, c = idx & 7;
                    char* baseB = (char*)Bs + (size_t)(it * 256 + (tid & ~63)) * 16;
                    gll16(Bb + (size_t)(mt * 128 + brow) * 1024 + ks * 64 + (c ^ (brow & 7)) * 8,
                          baseB);
                }
            }
            __syncthreads();  // staging visible (compiler drains vmcnt/lgkmcnt)

            const char* xb = (const char*)Xs + (wr * 64 + l15) * 128;
            const char* bb = (const char*)Bs + (wc * 64 + l15) * 128;
            const int sw = (l15 & 7) << 4;
#pragma unroll
            for (int kk = 0; kk < 2; ++kk) {
                const int ob = (kk * 64 + lg * 16) ^ sw;
                bf16x8 a[4], bq[4];
#pragma unroll
                for (int mi = 0; mi < 4; ++mi) a[mi] = *(const bf16x8*)(xb + mi * 2048 + ob);
#pragma unroll
                for (int ni = 0; ni < 4; ++ni) bq[ni] = *(const bf16x8*)(bb + ni * 2048 + ob);
#pragma unroll
                for (int mi = 0; mi < 4; ++mi)
#pragma unroll
                    for (int ni = 0; ni < 4; ++ni)
                        acc[mi][ni] = __builtin_amdgcn_mfma_f32_16x16x32_bf16(
                            a[mi], bq[ni], acc[mi][ni], 0, 0, 0);
            }
        }
        // fold squares into per-token partial (C/D: col=lane&15 -> m, row=lg*4+r -> token)
#pragma unroll
        for (int mi = 0; mi < 4; ++mi)
#pragma unroll
            for (int ni = 0; ni < 4; ++ni)
#pragma unroll
                for (int r = 0; r < 4; ++r)
                    nsq_reg[mi][r] += acc[mi][ni][r] * acc[mi][ni][r];
    }

    if (tid < 128) nsq_s[tid] = 0.f;
    __syncthreads();
#pragma unroll
    for (int mi = 0; mi < 4; ++mi)
#pragma unroll
        for (int r = 0; r < 4; ++r) {
            float v = nsq_reg[mi][r];
            v += __shfl_xor(v, 1);
            v += __shfl_xor(v, 2);
            v += __shfl_xor(v, 4);
            v += __shfl_xor(v, 8);
            if (l15 == 0) atomicAdd(&nsq_s[wr * 64 + mi * 16 + lg * 4 + r], v);
        }
    __syncthreads();
    if (tid < 128) nsq_g[(size_t)mh * 65536 + st + tid] = nsq_s[tid];
}

// ---- pass 4: numer, sim, out partials (no global atomics) ----
template <int XBF>
__global__ __launch_bounds__(256, 2) void k_finish(
    const float* __restrict__ x, const unsigned short* __restrict__ xbf,
    const float* __restrict__ w, const float* __restrict__ nsq_g,
    float* __restrict__ outp, float* __restrict__ sim_out) {
    __shared__ unsigned short xt[32 * 1024];  // 64 KB, XOR-swizzled bf16 tile
    __shared__ float numer[32];
    __shared__ float simv[32];

    const int tid = threadIdx.x;
    const int bs = blockIdx.x;
    const int b = bs >> 7, s0 = (bs & 127) * 32;
    const size_t tok0 = (size_t)b * 4096 + s0;

    if (XBF) {
#pragma unroll
        for (int it = 0; it < 16; ++it) {
            const int idx = it * 256 + tid;
            const int row = idx >> 7, c = idx & 127;
            char* base = (char*)xt + (size_t)(it * 256 + (tid & ~63)) * 16;
            gll16(xbf + (tok0 + row) * 1024 + ((c ^ (row & 7)) * 8), base);
        }
    } else {
        const float4* src = (const float4*)(x + tok0 * 1024) + tid;
        char* lds = (char*)xt;
        for (int r = 0; r < 32; ++r) {
            float4 v = src[r * 256];
            uint2 p;
            p.x = f2bf(v.x) | (f2bf(v.y) << 16);
            p.y = f2bf(v.z) | (f2bf(v.w) << 16);
            *(uint2*)(lds + r * 2048 + ((tid * 8) ^ ((r & 7) << 4))) = p;
        }
    }
    __syncthreads();

    // numerator: w[b] . x[token]  (8 lanes per token)
    {
        const int t = tid >> 3, kp = tid & 7;
        const float* wb = w + (size_t)b * 1024 + kp * 128;
        const char* pt = (const char*)xt + t * 2048;
        const int sw2 = (t & 7) << 4;
        float acc = 0.f;
#pragma unroll
        for (int j = 0; j < 16; ++j) {
            const int kb = (kp * 128 + j * 8) * 2;
            bf16x8 v = *(const bf16x8*)(pt + (kb ^ sw2));
#pragma unroll
            for (int e = 0; e < 8; ++e) acc += (float)v[e] * wb[j * 8 + e];
        }
        acc += __shfl_xor(acc, 1);
        acc += __shfl_xor(acc, 2);
        acc += __shfl_xor(acc, 4);
        if (kp == 0) numer[t] = acc;
    }
    __syncthreads();

    if (tid < 32) {
        float nt = nsq_g[tok0 + tid] + nsq_g[65536 + tok0 + tid];
        float s = numer[tid] / (EPS + sqrtf(nt));
        simv[tid] = s;
        sim_out[tok0 + tid] = s;
    }
    __syncthreads();

    // out partial for this 32-token tile (plain store; reduced in k_outred)
    {
        const int n0 = tid * 4;
        float a0 = 0.f, a1 = 0.f, a2 = 0.f, a3 = 0.f;
        const char* lds = (const char*)xt;
#pragma unroll 4
        for (int t = 0; t < 32; ++t) {
            int byte = t * 2048 + ((n0 * 2) ^ ((t & 7) << 4));
            bf16x4 v = *(const bf16x4*)(lds + byte);
            float s = simv[t];
            a0 += s * (float)v[0];
            a1 += s * (float)v[1];
            a2 += s * (float)v[2];
            a3 += s * (float)v[3];
        }
        float4 o; o.x = a0; o.y = a1; o.z = a2; o.w = a3;
        ((float4*)(outp + (size_t)bs * 1024))[tid] = o;
    }
}

// ---- out[b][j] = sum over 128 tile partials ----
__global__ void k_outred(const float* __restrict__ outp, float* __restrict__ out) {
    const int b = blockIdx.y, j = blockIdx.x * 256 + threadIdx.x;
    const float* p = outp + (size_t)b * 128 * 1024 + j;
    float s = 0.f;
    for (int t = 0; t < 128; ++t) s += p[t * 1024];
    out[b * 1024 + j] = s;
}

extern "C" void kernel_launch(void* const* d_in, const int* in_sizes, int n_in,
                              void* d_out, int out_size, void* d_ws, size_t ws_size,
                              hipStream_t stream) {
    const float* x = (const float*)d_in[0];  // [16][4096][1024]
    const float* A = (const float*)d_in[1];  // [1024][1024]
    const float* B = (const float*)d_in[2];  // [1024][1024]
    float* out = (float*)d_out;              // [16][1024] then sim [16][4096]
    float* sim = out + 16 * 1024;
    float* ws = (float*)d_ws;
    // workspace layout (float offsets)
    float* xs_part = ws;                                  // 524288  (2 MB)
    float* xs = ws + 524288;                              // 16384
    float* q = ws + 540672;                               // 16384
    float* wv = ws + 557056;                              // 16384
    float* nsq = ws + 573440;                             // 131072 (2 planes)
    float* outp = ws + 704512;                            // 2097152 (8 MB)
    unsigned short* Bb = (unsigned short*)(ws + 2801664); // 1M bf16 (2 MB)
    unsigned short* xbf = (unsigned short*)(ws + 3325952);// 64M bf16 (128 MB, optional)
    const bool xb = ws_size >= (size_t)(3325952 + 33554432) * 4;

    if (xb) k_prep<1><<<dim3(32, 16), 256, 0, stream>>>(x, xs_part, xbf);
    else    k_prep<0><<<dim3(32, 16), 256, 0, stream>>>(x, xs_part, (unsigned short*)0);
    k_bconv<<<1024, 256, 0, stream>>>(B, Bb);
    k_xsred<<<dim3(4, 16), 256, 0, stream>>>(xs_part, xs);
    k_query<<<dim3(4, 16), 256, 0, stream>>>(A, xs, q);
    k_qnorm<<<16, 256, 0, stream>>>(q);
    k_w<<<dim3(4, 16), 256, 0, stream>>>(B, q, wv);
    if (xb) k_nsq<1><<<dim3(512, 2), 256, 0, stream>>>(x, xbf, Bb, nsq);
    else    k_nsq<0><<<dim3(512, 2), 256, 0, stream>>>(x, xbf, Bb, nsq);
    if (xb) k_finish<1><<<2048, 256, 0, stream>>>(x, xbf, wv, nsq, outp, sim);
    else    k_finish<0><<<2048, 256, 0, stream>>>(x, xbf, wv, nsq, outp, sim);
    k_outred<<<dim3(4, 16), 256, 0, stream>>>(outp, out);
}

// Round 2
// 324.818 us; speedup vs baseline: 2.5498x; 1.1287x over previous
//
#include <hip/hip_runtime.h>

#define EPS 1e-5f

typedef __bf16 bf16x8 __attribute__((ext_vector_type(8)));
typedef __bf16 bf16x4 __attribute__((ext_vector_type(4)));
typedef float f32x4 __attribute__((ext_vector_type(4)));

static __device__ __forceinline__ unsigned int f2bf(float f) {
    unsigned int u = __builtin_bit_cast(unsigned int, f);
    u = (u + 0x7fffu + ((u >> 16) & 1u)) >> 16;
    return u;
}

// async global->LDS, 16B per lane. LDS dest is wave-uniform base (+lane*16 by HW).
static __device__ __forceinline__ void gll16(const void* g, void* l) {
    __builtin_amdgcn_global_load_lds(
        (const __attribute__((address_space(1))) unsigned int*)(unsigned long long)g,
        (__attribute__((address_space(3))) unsigned int*)(unsigned int)(unsigned long long)l,
        16, 0, 0);
}

// ---- pass 1: colsum partials (+ optional bf16 copy of x) ----
template <int XBF>
__global__ __launch_bounds__(256) void k_prep(const float* __restrict__ x,
                                              float* __restrict__ xs_part,
                                              unsigned short* __restrict__ xbf) {
    const int b = blockIdx.y, sc = blockIdx.x, tid = threadIdx.x;
    const size_t rowbase = ((size_t)(b * 4096 + sc * 128)) * 1024;
    const float4* src = (const float4*)(x + rowbase) + tid;
    uint2* dst = XBF ? ((uint2*)(xbf + rowbase) + tid) : (uint2*)0;
    float ax = 0.f, ay = 0.f, az = 0.f, aw = 0.f;
    for (int r = 0; r < 128; ++r) {
        float4 v = src[r * 256];
        ax += v.x; ay += v.y; az += v.z; aw += v.w;
        if (XBF) {
            uint2 p;
            p.x = f2bf(v.x) | (f2bf(v.y) << 16);
            p.y = f2bf(v.z) | (f2bf(v.w) << 16);
            dst[r * 256] = p;
        }
    }
    float4 o; o.x = ax; o.y = ay; o.z = az; o.w = aw;
    ((float4*)(xs_part + ((size_t)(b * 32 + sc)) * 1024))[tid] = o;
}

// ---- xs[b][j] = sum over 32 partials ----
__global__ void k_xsred(const float* __restrict__ xs_part, float* __restrict__ xs) {
    const int b = blockIdx.y, j = blockIdx.x * 256 + threadIdx.x;
    const float* p = xs_part + (size_t)b * 32 * 1024 + j;
    float s = 0.f;
#pragma unroll
    for (int sc = 0; sc < 32; ++sc) s += p[sc * 1024];
    xs[b * 1024 + j] = s;
}

// ---- convert B (f32 [1024][1024]) -> bf16 ----
__global__ void k_bconv(const float* __restrict__ B, unsigned short* __restrict__ Bb) {
    const int i = blockIdx.x * 256 + threadIdx.x;
    float4 v = ((const float4*)B)[i];
    uint2 p;
    p.x = f2bf(v.x) | (f2bf(v.y) << 16);
    p.y = f2bf(v.z) | (f2bf(v.w) << 16);
    ((uint2*)Bb)[i] = p;
}

// ---- query[b,i] = dot(A[i,:], xs[b,:]) ----
__global__ void k_query(const float* __restrict__ A, const float* __restrict__ xs,
                        float* __restrict__ q) {
    const int b = blockIdx.y;
    const int i = blockIdx.x * 256 + threadIdx.x;
    const float4* ar = (const float4*)(A + (size_t)i * 1024);
    const float4* xr = (const float4*)(xs + b * 1024);
    float acc = 0.f;
    for (int k = 0; k < 256; ++k) {
        float4 a = ar[k], v = xr[k];
        acc += a.x * v.x + a.y * v.y + a.z * v.z + a.w * v.w;
    }
    q[b * 1024 + i] = acc;
}

// ---- normalize query rows in place ----
__global__ void k_qnorm(float* q) {
    const int b = blockIdx.x, tid = threadIdx.x;
    float4* qp = (float4*)(q + (size_t)b * 1024);
    float4 v = qp[tid];
    float ss = v.x * v.x + v.y * v.y + v.z * v.z + v.w * v.w;
    for (int o = 1; o < 64; o <<= 1) ss += __shfl_xor(ss, o);
    __shared__ float wsum[4];
    if ((tid & 63) == 0) wsum[tid >> 6] = ss;
    __syncthreads();
    float inv = 1.f / (EPS + sqrtf(wsum[0] + wsum[1] + wsum[2] + wsum[3]));
    v.x *= inv; v.y *= inv; v.z *= inv; v.w *= inv;
    qp[tid] = v;
}

// ---- w[b,j] = sum_i B[i,j] * qhat[b,i] ----
__global__ void k_w(const float* __restrict__ B, const float* __restrict__ q,
                    float* __restrict__ w) {
    const int b = blockIdx.y;
    const int j = blockIdx.x * 256 + threadIdx.x;
    const float* qb = q + (size_t)b * 1024;
    float acc = 0.f;
    for (int i = 0; i < 1024; ++i) acc += B[(size_t)i * 1024 + j] * qb[i];
    w[b * 1024 + j] = acc;
}

// ---- pass 3 (fast path): nsq via 256x256 tile, counted-vmcnt deep pipeline ----
// grid = 256 blocks (1/CU), 512 threads (8 waves, 2M x 4N). Per block: 256 tokens,
// mt-loop over 4 m-tiles of 256; K=1024 in 16 steps of BK=64. Double-buffered LDS,
// tile staged 2 steps ahead; leading sync = s_waitcnt vmcnt(8) + raw s_barrier.
__global__ __launch_bounds__(512, 2) void k_nsq8(const unsigned short* __restrict__ xbf,
                                                 const unsigned short* __restrict__ Bb,
                                                 float* __restrict__ nsq_g) {
    __shared__ __align__(16) unsigned short Xs[2][256 * 64];  // 2 x 32 KB
    __shared__ __align__(16) unsigned short Bs[2][256 * 64];  // 2 x 32 KB
    __shared__ float nsq_s[256];

    const int tid = threadIdx.x;
    const int lane = tid & 63;
    const int l15 = lane & 15, lg = lane >> 4;
    const int w = tid >> 6;            // 0..7
    const int wm = w >> 2, wn = w & 3; // 2 x 4 wave grid
    const size_t tok0 = (size_t)blockIdx.x * 256;

    // stage step s (mt = s>>4, ks = s&15) into buffer `buf`.
    // chunk g = it*512+tid: row = g>>3 (0..255), c = g&7; linear LDS dest,
    // source chunk pre-swizzled c ^ (row&7)  (both-sides-or-neither rule).
#define STAGE(s_, buf_)                                                                  \
    do {                                                                                 \
        const int mt_ = (s_) >> 4, ks_ = (s_) & 15;                                      \
        _Pragma("unroll") for (int it = 0; it < 4; ++it) {                               \
            const int g_ = it * 512 + tid;                                               \
            const int row_ = g_ >> 3, c_ = g_ & 7;                                       \
            const int csw_ = (c_ ^ (row_ & 7)) * 8;                                      \
            char* bx_ = (char*)Xs[buf_] + (size_t)(it * 512 + (tid & ~63)) * 16;         \
            gll16(xbf + (tok0 + row_) * 1024 + ks_ * 64 + csw_, bx_);                    \
            char* bb_ = (char*)Bs[buf_] + (size_t)(it * 512 + (tid & ~63)) * 16;         \
            gll16(Bb + (size_t)(mt_ * 256 + row_) * 1024 + ks_ * 64 + csw_, bb_);        \
        }                                                                                \
    } while (0)

    float nsq_reg[8][4];
#pragma unroll
    for (int mi = 0; mi < 8; ++mi)
#pragma unroll
        for (int r = 0; r < 4; ++r) nsq_reg[mi][r] = 0.f;

    f32x4 acc[8][4];

    STAGE(0, 0);
    STAGE(1, 1);

    for (int s = 0; s < 64; ++s) {
        const int buf = s & 1;
        if ((s & 15) == 0) {
#pragma unroll
            for (int mi = 0; mi < 8; ++mi)
#pragma unroll
                for (int ni = 0; ni < 4; ++ni) acc[mi][ni] = (f32x4){0.f, 0.f, 0.f, 0.f};
        }
        // drain this step's tile (8 oldest loads); keep next tile's 8 in flight.
        if (s < 62) asm volatile("s_waitcnt vmcnt(8)" ::: "memory");
        else        asm volatile("s_waitcnt vmcnt(0)" ::: "memory");
        __builtin_amdgcn_s_barrier();

        const char* xb = (const char*)Xs[buf] + (wm * 128 + l15) * 128;
        const char* bb = (const char*)Bs[buf] + (wn * 64 + l15) * 128;
        const int sw = (l15 & 7) << 4;

        bf16x8 bq[4][2];
#pragma unroll
        for (int ni = 0; ni < 4; ++ni)
#pragma unroll
            for (int kk = 0; kk < 2; ++kk)
                bq[ni][kk] = *(const bf16x8*)(bb + ni * 16 * 128 + ((kk * 64 + lg * 16) ^ sw));

        __builtin_amdgcn_s_setprio(1);
#pragma unroll
        for (int p = 0; p < 4; ++p) {
            bf16x8 a[2][2];
#pragma unroll
            for (int mi = 0; mi < 2; ++mi)
#pragma unroll
                for (int kk = 0; kk < 2; ++kk)
                    a[mi][kk] = *(const bf16x8*)(xb + (p * 2 + mi) * 16 * 128 +
                                                 ((kk * 64 + lg * 16) ^ sw));
#pragma unroll
            for (int mi = 0; mi < 2; ++mi)
#pragma unroll
                for (int ni = 0; ni < 4; ++ni)
#pragma unroll
                    for (int kk = 0; kk < 2; ++kk)
                        acc[p * 2 + mi][ni] = __builtin_amdgcn_mfma_f32_16x16x32_bf16(
                            a[mi][kk], bq[ni][kk], acc[p * 2 + mi][ni], 0, 0, 0);
        }
        __builtin_amdgcn_s_setprio(0);

        asm volatile("" ::: "memory");
        __builtin_amdgcn_s_barrier();  // all waves done reading buf; safe to overwrite
        asm volatile("" ::: "memory");
        if (s + 2 < 64) STAGE(s + 2, buf);

        if ((s & 15) == 15) {  // end of m-tile: fold squares (register-only)
#pragma unroll
            for (int mi = 0; mi < 8; ++mi)
#pragma unroll
                for (int ni = 0; ni < 4; ++ni)
#pragma unroll
                    for (int r = 0; r < 4; ++r)
                        nsq_reg[mi][r] += acc[mi][ni][r] * acc[mi][ni][r];
        }
    }
#undef STAGE

    if (tid < 256) nsq_s[tid] = 0.f;
    __syncthreads();
#pragma unroll
    for (int mi = 0; mi < 8; ++mi)
#pragma unroll
        for (int r = 0; r < 4; ++r) {
            float v = nsq_reg[mi][r];
            v += __shfl_xor(v, 1);
            v += __shfl_xor(v, 2);
            v += __shfl_xor(v, 4);
            v += __shfl_xor(v, 8);
            if (l15 == 0) atomicAdd(&nsq_s[wm * 128 + mi * 16 + lg * 4 + r], v);
        }
    __syncthreads();
    if (tid < 256) nsq_g[tok0 + tid] = nsq_s[tid];
}

// ---- pass 3 (fallback, no xbf workspace): 128x128 tile from f32 x ----
__global__ __launch_bounds__(256, 2) void k_nsq_f32(const float* __restrict__ x,
                                                    const unsigned short* __restrict__ Bb,
                                                    float* __restrict__ nsq_g) {
    __shared__ unsigned short Xs[128 * 64];
    __shared__ unsigned short Bs[128 * 64];
    __shared__ float nsq_s[128];

    const int tid = threadIdx.x;
    const int lane = tid & 63;
    const int l15 = lane & 15, lg = lane >> 4;
    const int w = tid >> 6;
    const int wr = w >> 1, wc = w & 1;
    const int st = blockIdx.x * 128;
    const int mh = blockIdx.y;

    float nsq_reg[4][4];
#pragma unroll
    for (int mi = 0; mi < 4; ++mi)
#pragma unroll
        for (int r = 0; r < 4; ++r) nsq_reg[mi][r] = 0.f;

    for (int mti = 0; mti < 4; ++mti) {
        const int mt = mh * 4 + mti;
        f32x4 acc[4][4];
#pragma unroll
        for (int mi = 0; mi < 4; ++mi)
#pragma unroll
            for (int ni = 0; ni < 4; ++ni) acc[mi][ni] = (f32x4){0.f, 0.f, 0.f, 0.f};

        for (int ks = 0; ks < 16; ++ks) {
            __syncthreads();
            {
                const int row = tid >> 1, kh = tid & 1;
                const float* srcx = x + (size_t)(st + row) * 1024 + ks * 64 + kh * 32;
                char* ldsrow = (char*)Xs + row * 128;
                const int sw = (row & 7) << 4;
#pragma unroll
                for (int j = 0; j < 4; ++j) {
                    float4 v0 = ((const float4*)srcx)[j * 2];
                    float4 v1 = ((const float4*)srcx)[j * 2 + 1];
                    uint4 p;
                    p.x = f2bf(v0.x) | (f2bf(v0.y) << 16);
                    p.y = f2bf(v0.z) | (f2bf(v0.w) << 16);
                    p.z = f2bf(v1.x) | (f2bf(v1.y) << 16);
                    p.w = f2bf(v1.z) | (f2bf(v1.w) << 16);
                    *(uint4*)(ldsrow + (((kh * 4 + j) * 16) ^ sw)) = p;
                }
#pragma unroll
                for (int it = 0; it < 4; ++it) {
                    const int idx = it * 256 + tid;
                    const int brow = idx >> 3, c = idx & 7;
                    char* baseB = (char*)Bs + (size_t)(it * 256 + (tid & ~63)) * 16;
                    gll16(Bb + (size_t)(mt * 128 + brow) * 1024 + ks * 64 + (c ^ (brow & 7)) * 8,
                          baseB);
                }
            }
            __syncthreads();

            const char* xb = (const char*)Xs + (wr * 64 + l15) * 128;
            const char* bb = (const char*)Bs + (wc * 64 + l15) * 128;
            const int sw = (l15 & 7) << 4;
#pragma unroll
            for (int kk = 0; kk < 2; ++kk) {
                const int ob = (kk * 64 + lg * 16) ^ sw;
                bf16x8 a[4], bq[4];
#pragma unroll
                for (int mi = 0; mi < 4; ++mi) a[mi] = *(const bf16x8*)(xb + mi * 2048 + ob);
#pragma unroll
                for (int ni = 0; ni < 4; ++ni) bq[ni] = *(const bf16x8*)(bb + ni * 2048 + ob);
#pragma unroll
                for (int mi = 0; mi < 4; ++mi)
#pragma unroll
                    for (int ni = 0; ni < 4; ++ni)
                        acc[mi][ni] = __builtin_amdgcn_mfma_f32_16x16x32_bf16(
                            a[mi], bq[ni], acc[mi][ni], 0, 0, 0);
            }
        }
#pragma unroll
        for (int mi = 0; mi < 4; ++mi)
#pragma unroll
            for (int ni = 0; ni < 4; ++ni)
#pragma unroll
                for (int r = 0; r < 4; ++r)
                    nsq_reg[mi][r] += acc[mi][ni][r] * acc[mi][ni][r];
    }

    if (tid < 128) nsq_s[tid] = 0.f;
    __syncthreads();
#pragma unroll
    for (int mi = 0; mi < 4; ++mi)
#pragma unroll
        for (int r = 0; r < 4; ++r) {
            float v = nsq_reg[mi][r];
            v += __shfl_xor(v, 1);
            v += __shfl_xor(v, 2);
            v += __shfl_xor(v, 4);
            v += __shfl_xor(v, 8);
            if (l15 == 0) atomicAdd(&nsq_s[wr * 64 + mi * 16 + lg * 4 + r], v);
        }
    __syncthreads();
    if (tid < 128) nsq_g[(size_t)mh * 65536 + st + tid] = nsq_s[tid];
}

// ---- pass 4: numer, sim, out partials (no global atomics) ----
template <int XBF>
__global__ __launch_bounds__(256, 2) void k_finish(
    const float* __restrict__ x, const unsigned short* __restrict__ xbf,
    const float* __restrict__ w, const float* __restrict__ nsq_g,
    float* __restrict__ outp, float* __restrict__ sim_out) {
    __shared__ __align__(16) unsigned short xt[32 * 1024];  // 64 KB
    __shared__ float numer[32];
    __shared__ float simv[32];

    const int tid = threadIdx.x;
    const int bs = blockIdx.x;
    const int b = bs >> 7, s0 = (bs & 127) * 32;
    const size_t tok0 = (size_t)b * 4096 + s0;

    if (XBF) {
#pragma unroll
        for (int it = 0; it < 16; ++it) {
            const int idx = it * 256 + tid;
            const int row = idx >> 7, c = idx & 127;
            char* base = (char*)xt + (size_t)(it * 256 + (tid & ~63)) * 16;
            gll16(xbf + (tok0 + row) * 1024 + ((c ^ (row & 7)) * 8), base);
        }
    } else {
        const float4* src = (const float4*)(x + tok0 * 1024) + tid;
        char* lds = (char*)xt;
        for (int r = 0; r < 32; ++r) {
            float4 v = src[r * 256];
            uint2 p;
            p.x = f2bf(v.x) | (f2bf(v.y) << 16);
            p.y = f2bf(v.z) | (f2bf(v.w) << 16);
            *(uint2*)(lds + r * 2048 + ((tid * 8) ^ ((r & 7) << 4))) = p;
        }
    }
    __syncthreads();

    {
        const int t = tid >> 3, kp = tid & 7;
        const float* wb = w + (size_t)b * 1024 + kp * 128;
        const char* pt = (const char*)xt + t * 2048;
        const int sw2 = (t & 7) << 4;
        float acc = 0.f;
#pragma unroll
        for (int j = 0; j < 16; ++j) {
            const int kb = (kp * 128 + j * 8) * 2;
            bf16x8 v = *(const bf16x8*)(pt + (kb ^ sw2));
#pragma unroll
            for (int e = 0; e < 8; ++e) acc += (float)v[e] * wb[j * 8 + e];
        }
        acc += __shfl_xor(acc, 1);
        acc += __shfl_xor(acc, 2);
        acc += __shfl_xor(acc, 4);
        if (kp == 0) numer[t] = acc;
    }
    __syncthreads();

    if (tid < 32) {
        float nt = XBF ? nsq_g[tok0 + tid] : (nsq_g[tok0 + tid] + nsq_g[65536 + tok0 + tid]);
        float s = numer[tid] / (EPS + sqrtf(nt));
        simv[tid] = s;
        sim_out[tok0 + tid] = s;
    }
    __syncthreads();

    {
        const int n0 = tid * 4;
        float a0 = 0.f, a1 = 0.f, a2 = 0.f, a3 = 0.f;
        const char* lds = (const char*)xt;
#pragma unroll 4
        for (int t = 0; t < 32; ++t) {
            int byte = t * 2048 + ((n0 * 2) ^ ((t & 7) << 4));
            bf16x4 v = *(const bf16x4*)(lds + byte);
            float s = simv[t];
            a0 += s * (float)v[0];
            a1 += s * (float)v[1];
            a2 += s * (float)v[2];
            a3 += s * (float)v[3];
        }
        float4 o; o.x = a0; o.y = a1; o.z = a2; o.w = a3;
        ((float4*)(outp + (size_t)bs * 1024))[tid] = o;
    }
}

// ---- out[b][j] = sum over 128 tile partials ----
__global__ void k_outred(const float* __restrict__ outp, float* __restrict__ out) {
    const int b = blockIdx.y, j = blockIdx.x * 256 + threadIdx.x;
    const float* p = outp + (size_t)b * 128 * 1024 + j;
    float s = 0.f;
    for (int t = 0; t < 128; ++t) s += p[t * 1024];
    out[b * 1024 + j] = s;
}

extern "C" void kernel_launch(void* const* d_in, const int* in_sizes, int n_in,
                              void* d_out, int out_size, void* d_ws, size_t ws_size,
                              hipStream_t stream) {
    const float* x = (const float*)d_in[0];  // [16][4096][1024]
    const float* A = (const float*)d_in[1];  // [1024][1024]
    const float* B = (const float*)d_in[2];  // [1024][1024]
    float* out = (float*)d_out;              // [16][1024] then sim [16][4096]
    float* sim = out + 16 * 1024;
    float* ws = (float*)d_ws;
    float* xs_part = ws;                                  // 524288  (2 MB)
    float* xs = ws + 524288;                              // 16384
    float* q = ws + 540672;                               // 16384
    float* wv = ws + 557056;                              // 16384
    float* nsq = ws + 573440;                             // 131072 (fallback uses 2 planes)
    float* outp = ws + 704512;                            // 2097152 (8 MB)
    unsigned short* Bb = (unsigned short*)(ws + 2801664); // 1M bf16 (2 MB)
    unsigned short* xbf = (unsigned short*)(ws + 3325952);// 64M bf16 (128 MB, optional)
    const bool xb = ws_size >= (size_t)(3325952 + 33554432) * 4;

    if (xb) k_prep<1><<<dim3(32, 16), 256, 0, stream>>>(x, xs_part, xbf);
    else    k_prep<0><<<dim3(32, 16), 256, 0, stream>>>(x, xs_part, (unsigned short*)0);
    k_bconv<<<1024, 256, 0, stream>>>(B, Bb);
    k_xsred<<<dim3(4, 16), 256, 0, stream>>>(xs_part, xs);
    k_query<<<dim3(4, 16), 256, 0, stream>>>(A, xs, q);
    k_qnorm<<<16, 256, 0, stream>>>(q);
    k_w<<<dim3(4, 16), 256, 0, stream>>>(B, q, wv);
    if (xb) k_nsq8<<<256, 512, 0, stream>>>(xbf, Bb, nsq);
    else    k_nsq_f32<<<dim3(512, 2), 256, 0, stream>>>(x, Bb, nsq);
    if (xb) k_finish<1><<<2048, 256, 0, stream>>>(x, xbf, wv, nsq, outp, sim);
    else    k_finish<0><<<2048, 256, 0, stream>>>(x, xbf, wv, nsq, outp, sim);
    k_outred<<<dim3(4, 16), 256, 0, stream>>>(outp, out);
}

// Round 4
// 300.662 us; speedup vs baseline: 2.7546x; 1.0803x over previous
//
#include <hip/hip_runtime.h>

#define EPS 1e-5f

typedef __bf16 bf16x8 __attribute__((ext_vector_type(8)));
typedef __bf16 bf16x4 __attribute__((ext_vector_type(4)));
typedef __bf16 bf16x2 __attribute__((ext_vector_type(2)));
typedef float f32x4 __attribute__((ext_vector_type(4)));

static __device__ __forceinline__ unsigned int f2bf(float f) {
    unsigned int u = __builtin_bit_cast(unsigned int, f);
    u = (u + 0x7fffu + ((u >> 16) & 1u)) >> 16;
    return u;
}

// async global->LDS, 16B per lane. LDS dest is wave-uniform base (+lane*16 by HW).
static __device__ __forceinline__ void gll16(const void* g, void* l) {
    __builtin_amdgcn_global_load_lds(
        (const __attribute__((address_space(1))) unsigned int*)(unsigned long long)g,
        (__attribute__((address_space(3))) unsigned int*)(unsigned int)(unsigned long long)l,
        16, 0, 0);
}

// ---- pass 1: colsum partials (+ optional bf16 copy of x) ----
template <int XBF>
__global__ __launch_bounds__(256) void k_prep(const float* __restrict__ x,
                                              float* __restrict__ xs_part,
                                              unsigned short* __restrict__ xbf) {
    const int b = blockIdx.y, sc = blockIdx.x, tid = threadIdx.x;
    const size_t rowbase = ((size_t)(b * 4096 + sc * 128)) * 1024;
    const float4* src = (const float4*)(x + rowbase) + tid;
    uint2* dst = XBF ? ((uint2*)(xbf + rowbase) + tid) : (uint2*)0;
    float ax = 0.f, ay = 0.f, az = 0.f, aw = 0.f;
    for (int r = 0; r < 128; ++r) {
        float4 v = src[r * 256];
        ax += v.x; ay += v.y; az += v.z; aw += v.w;
        if (XBF) {
            uint2 p;
            p.x = f2bf(v.x) | (f2bf(v.y) << 16);
            p.y = f2bf(v.z) | (f2bf(v.w) << 16);
            dst[r * 256] = p;
        }
    }
    float4 o; o.x = ax; o.y = ay; o.z = az; o.w = aw;
    ((float4*)(xs_part + ((size_t)(b * 32 + sc)) * 1024))[tid] = o;
}

// ---- convert B (f32 [1024][1024]) -> bf16 ----
__global__ void k_bconv(const float* __restrict__ B, unsigned short* __restrict__ Bb) {
    const int i = blockIdx.x * 256 + threadIdx.x;
    float4 v = ((const float4*)B)[i];
    uint2 p;
    p.x = f2bf(v.x) | (f2bf(v.y) << 16);
    p.y = f2bf(v.z) | (f2bf(v.w) << 16);
    ((uint2*)Bb)[i] = p;
}

// ---- fused xsred + query: q[b,i] = dot(A[i,:], sum_s x[b,s,:]) ----
__global__ __launch_bounds__(256) void k_queryf(const float* __restrict__ xs_part,
                                                const float* __restrict__ A,
                                                float* __restrict__ q) {
    __shared__ float xsl[1024];
    const int b = blockIdx.y, g = blockIdx.x, tid = threadIdx.x;
    {
        float4 s4 = {0.f, 0.f, 0.f, 0.f};
        const float4* p = (const float4*)(xs_part + (size_t)b * 32768) + tid;
        for (int sc = 0; sc < 32; ++sc) {
            float4 v = p[sc * 256];
            s4.x += v.x; s4.y += v.y; s4.z += v.z; s4.w += v.w;
        }
        ((float4*)xsl)[tid] = s4;
    }
    __syncthreads();
    const int i = g * 256 + tid;
    const float4* ar = (const float4*)(A + (size_t)i * 1024);
    float acc = 0.f;
    for (int k = 0; k < 256; ++k) {
        float4 a = ar[k], v = ((const float4*)xsl)[k];
        acc += a.x * v.x + a.y * v.y + a.z * v.z + a.w * v.w;
    }
    q[b * 1024 + i] = acc;
}

// ---- fused qnorm + w: w[b,j] = sum_i B[i,j] * (q[b,i]/||q[b]||) ----
__global__ __launch_bounds__(256) void k_wf(const float* __restrict__ B,
                                            const float* __restrict__ q,
                                            float* __restrict__ w) {
    __shared__ float ql[1024];
    __shared__ float wsum[4];
    const int b = blockIdx.y, g = blockIdx.x, tid = threadIdx.x;
    float4 v = ((const float4*)(q + (size_t)b * 1024))[tid];
    float ss = v.x * v.x + v.y * v.y + v.z * v.z + v.w * v.w;
    for (int o = 1; o < 64; o <<= 1) ss += __shfl_xor(ss, o);
    if ((tid & 63) == 0) wsum[tid >> 6] = ss;
    __syncthreads();
    const float inv = 1.f / (EPS + sqrtf(wsum[0] + wsum[1] + wsum[2] + wsum[3]));
    float4 n; n.x = v.x * inv; n.y = v.y * inv; n.z = v.z * inv; n.w = v.w * inv;
    ((float4*)ql)[tid] = n;
    __syncthreads();
    const int j = g * 256 + tid;
    float acc = 0.f;
    for (int i = 0; i < 1024; ++i) acc += B[(size_t)i * 1024 + j] * ql[i];
    w[b * 1024 + j] = acc;
}

// ---- fused main: nsq GEMM (256tok x 1024m, phase-aligned prefetch) + finish ----
// grid = 256 blocks (1/CU), 512 threads (8 waves, 2M x 4N over 256x256 sub-tile).
// Race-safety: stage parts for step s+2 are issued only after the barrier that
// proves all waves finished reading that region of buf(s) (B free after phase 0;
// X rows {p*32..+31}u{128+p*32..+31} free after phase p).
__global__ __launch_bounds__(512, 2) void k_main2(const unsigned short* __restrict__ xbf,
                                                  const unsigned short* __restrict__ Bb,
                                                  const float* __restrict__ w,
                                                  float* __restrict__ outp,
                                                  float* __restrict__ sim_out) {
    __shared__ __align__(16) union {
        struct { unsigned short Xs[2][256 * 64]; unsigned short Bs[2][256 * 64]; } g;
        unsigned short xt[32 * 1024];
    } S;
    __shared__ float nsq_s[256];
    __shared__ float wlds[1024];
    __shared__ float numer_s[32];
    __shared__ float simv[32];

    const int tid = threadIdx.x;
    const int lane = tid & 63;
    const int l15 = lane & 15, lg = lane >> 4;
    const int w8 = tid >> 6;
    const int wm = w8 >> 2, wn = w8 & 3;
    const int bx = blockIdx.x;
    const size_t tok0 = (size_t)bx * 256;
    const int b = bx >> 4;

    ((float2*)wlds)[tid] = ((const float2*)(w + (size_t)b * 1024))[tid];
    if (tid < 256) nsq_s[tid] = 0.f;

    // B part it (rows it*64..it*64+63) of step ts into buffer bf (linear dest,
    // pre-swizzled source chunk: both-sides-or-neither).
#define STAGE_B(ts_, bf_, it_)                                                            \
    do {                                                                                  \
        const int mt_ = (ts_) >> 4, ks_ = (ts_) & 15;                                     \
        const int g_ = (it_) * 512 + tid;                                                 \
        const int row_ = g_ >> 3, c_ = g_ & 7;                                            \
        gll16(Bb + (size_t)(mt_ * 256 + row_) * 1024 + ks_ * 64 + ((c_ ^ (row_ & 7)) * 8),\
              (char*)S.g.Bs[bf_] + (size_t)((it_) * 512 + (tid & ~63)) * 16);             \
    } while (0)
    // X part p (rows p*32..p*32+31 and 128+p*32..128+p*32+31) of step ts.
    // wave w<4 -> rows p*32+w*8.., wave w>=4 -> rows 128+p*32+(w-4)*8..
    // (each wave writes one contiguous 1KB LDS run = gll16 HW requirement)
#define STAGE_X(ts_, bf_, p_)                                                             \
    do {                                                                                  \
        const int ks_ = (ts_) & 15;                                                       \
        const int w_ = tid >> 6;                                                          \
        const int ar0_ = (w_ < 4) ? ((p_) * 32 + w_ * 8) : (128 + (p_) * 32 + (w_ - 4) * 8); \
        const int ar_ = ar0_ + ((tid & 63) >> 3);                                         \
        const int c_ = tid & 7;                                                           \
        gll16(xbf + (tok0 + ar_) * 1024 + ks_ * 64 + ((c_ ^ (ar_ & 7)) * 8),              \
              (char*)S.g.Xs[bf_] + (size_t)ar0_ * 128);                                   \
    } while (0)

    f32x4 acc[8][4];

    // prologue: fully stage steps 0 and 1 (two contiguous groups of 8 loads)
#pragma unroll
    for (int it = 0; it < 4; ++it) STAGE_B(0, 0, it);
#pragma unroll
    for (int pp = 0; pp < 4; ++pp) STAGE_X(0, 0, pp);
#pragma unroll
    for (int it = 0; it < 4; ++it) STAGE_B(1, 1, it);
#pragma unroll
    for (int pp = 0; pp < 4; ++pp) STAGE_X(1, 1, pp);

    for (int s = 0; s < 64; ++s) {
        const int buf = s & 1;
        if ((s & 15) == 0) {
#pragma unroll
            for (int mi = 0; mi < 8; ++mi)
#pragma unroll
                for (int ni = 0; ni < 4; ++ni) acc[mi][ni] = (f32x4){0.f, 0.f, 0.f, 0.f};
        }
        // leading sync: drain this step's 8 loads (keep next step's 8 in flight)
        if (s < 62) asm volatile("s_waitcnt vmcnt(8)" ::: "memory");
        else        asm volatile("s_waitcnt vmcnt(0)" ::: "memory");
        __builtin_amdgcn_s_barrier();

        const char* xb = (const char*)S.g.Xs[buf] + (wm * 128 + l15) * 128;
        const char* bb = (const char*)S.g.Bs[buf] + (wn * 64 + l15) * 128;
        const int sw = (l15 & 7) << 4;
        const bool pre = (s + 2 < 64);

        bf16x8 bq[4][2];
#pragma unroll
        for (int ni = 0; ni < 4; ++ni)
#pragma unroll
            for (int kk = 0; kk < 2; ++kk)
                bq[ni][kk] = *(const bf16x8*)(bb + ni * 16 * 128 + ((kk * 64 + lg * 16) ^ sw));

#pragma unroll
        for (int p = 0; p < 4; ++p) {
            bf16x8 a[2][2];
#pragma unroll
            for (int mi = 0; mi < 2; ++mi)
#pragma unroll
                for (int kk = 0; kk < 2; ++kk)
                    a[mi][kk] = *(const bf16x8*)(xb + (p * 2 + mi) * 16 * 128 +
                                                 ((kk * 64 + lg * 16) ^ sw));
            // stage parts whose target region was freed by phase p-1
            if (pre) {
                if (p == 1) { STAGE_B(s + 2, buf, 0); STAGE_B(s + 2, buf, 1); STAGE_X(s + 2, buf, 0); }
                if (p == 2) { STAGE_B(s + 2, buf, 2); STAGE_B(s + 2, buf, 3); STAGE_X(s + 2, buf, 1); }
                if (p == 3) { STAGE_X(s + 2, buf, 2); }
            }
            asm volatile("" ::: "memory");
            __builtin_amdgcn_s_barrier();
            __builtin_amdgcn_s_setprio(1);
#pragma unroll
            for (int mi = 0; mi < 2; ++mi)
#pragma unroll
                for (int ni = 0; ni < 4; ++ni)
#pragma unroll
                    for (int kk = 0; kk < 2; ++kk)
                        acc[p * 2 + mi][ni] = __builtin_amdgcn_mfma_f32_16x16x32_bf16(
                            a[mi][kk], bq[ni][kk], acc[p * 2 + mi][ni], 0, 0, 0);
            __builtin_amdgcn_s_setprio(0);
            asm volatile("" ::: "memory");
            __builtin_amdgcn_s_barrier();  // phase-p reads complete chip-wide
        }
        if (pre) STAGE_X(s + 2, buf, 3);  // region freed by phase 3

        if ((s & 15) == 15) {  // end of m-tile: fold squares, reduce, LDS-atomic
#pragma unroll
            for (int mi = 0; mi < 8; ++mi)
#pragma unroll
                for (int r = 0; r < 4; ++r) {
                    float v = 0.f;
#pragma unroll
                    for (int ni = 0; ni < 4; ++ni) v += acc[mi][ni][r] * acc[mi][ni][r];
                    v += __shfl_xor(v, 1);
                    v += __shfl_xor(v, 2);
                    v += __shfl_xor(v, 4);
                    v += __shfl_xor(v, 8);
                    if (l15 == 0) atomicAdd(&nsq_s[wm * 128 + mi * 16 + lg * 4 + r], v);
                }
        }
    }
#undef STAGE_B
#undef STAGE_X
    __syncthreads();

    // ---- finish: per 32-token sub-tile: numer, sim, out-partial ----
    float oa0 = 0.f, oa1 = 0.f;
    for (int sub = 0; sub < 8; ++sub) {
#pragma unroll
        for (int it = 0; it < 8; ++it) {
            const int idx = it * 512 + tid;
            const int row = idx >> 7, c = idx & 127;
            gll16(xbf + (tok0 + sub * 32 + row) * 1024 + (c ^ (row & 7)) * 8,
                  (char*)S.xt + (size_t)(it * 512 + (tid & ~63)) * 16);
        }
        asm volatile("s_waitcnt vmcnt(0)" ::: "memory");
        __syncthreads();
        {
            const int t = tid >> 4, kp = tid & 15;
            const char* pt = (const char*)S.xt + t * 2048;
            const int sw2 = (t & 7) << 4;
            float acc2 = 0.f;
#pragma unroll
            for (int j = 0; j < 8; ++j) {
                bf16x8 v = *(const bf16x8*)(pt + ((j * 256 + kp * 16) ^ sw2));
                const float* wp = wlds + j * 128 + kp * 8;
#pragma unroll
                for (int e = 0; e < 8; ++e) acc2 += (float)v[e] * wp[e];
            }
            acc2 += __shfl_xor(acc2, 1);
            acc2 += __shfl_xor(acc2, 2);
            acc2 += __shfl_xor(acc2, 4);
            acc2 += __shfl_xor(acc2, 8);
            if (kp == 0) numer_s[t] = acc2;
        }
        __syncthreads();
        if (tid < 32) {
            float sv = numer_s[tid] / (EPS + sqrtf(nsq_s[sub * 32 + tid]));
            simv[tid] = sv;
            sim_out[tok0 + sub * 32 + tid] = sv;
        }
        __syncthreads();
        {
            const char* lds = (const char*)S.xt;
            const int nb = tid * 4;
#pragma unroll 4
            for (int t = 0; t < 32; ++t) {
                bf16x2 v = *(const bf16x2*)(lds + t * 2048 + (nb ^ ((t & 7) << 4)));
                float sv = simv[t];
                oa0 += sv * (float)v[0];
                oa1 += sv * (float)v[1];
            }
        }
        __syncthreads();
    }
    float2 o; o.x = oa0; o.y = oa1;
    ((float2*)(outp + (size_t)bx * 1024))[tid] = o;
}

// ---- fallback pass 3 (no xbf workspace): 128x128 tile from f32 x ----
__global__ __launch_bounds__(256, 2) void k_nsq_f32(const float* __restrict__ x,
                                                    const unsigned short* __restrict__ Bb,
                                                    float* __restrict__ nsq_g) {
    __shared__ unsigned short Xs[128 * 64];
    __shared__ unsigned short Bs[128 * 64];
    __shared__ float nsq_s[128];

    const int tid = threadIdx.x;
    const int lane = tid & 63;
    const int l15 = lane & 15, lg = lane >> 4;
    const int w = tid >> 6;
    const int wr = w >> 1, wc = w & 1;
    const int st = blockIdx.x * 128;
    const int mh = blockIdx.y;

    float nsq_reg[4][4];
#pragma unroll
    for (int mi = 0; mi < 4; ++mi)
#pragma unroll
        for (int r = 0; r < 4; ++r) nsq_reg[mi][r] = 0.f;

    for (int mti = 0; mti < 4; ++mti) {
        const int mt = mh * 4 + mti;
        f32x4 acc[4][4];
#pragma unroll
        for (int mi = 0; mi < 4; ++mi)
#pragma unroll
            for (int ni = 0; ni < 4; ++ni) acc[mi][ni] = (f32x4){0.f, 0.f, 0.f, 0.f};

        for (int ks = 0; ks < 16; ++ks) {
            __syncthreads();
            {
                const int row = tid >> 1, kh = tid & 1;
                const float* srcx = x + (size_t)(st + row) * 1024 + ks * 64 + kh * 32;
                char* ldsrow = (char*)Xs + row * 128;
                const int sw = (row & 7) << 4;
#pragma unroll
                for (int j = 0; j < 4; ++j) {
                    float4 v0 = ((const float4*)srcx)[j * 2];
                    float4 v1 = ((const float4*)srcx)[j * 2 + 1];
                    uint4 p;
                    p.x = f2bf(v0.x) | (f2bf(v0.y) << 16);
                    p.y = f2bf(v0.z) | (f2bf(v0.w) << 16);
                    p.z = f2bf(v1.x) | (f2bf(v1.y) << 16);
                    p.w = f2bf(v1.z) | (f2bf(v1.w) << 16);
                    *(uint4*)(ldsrow + (((kh * 4 + j) * 16) ^ sw)) = p;
                }
#pragma unroll
                for (int it = 0; it < 4; ++it) {
                    const int idx = it * 256 + tid;
                    const int brow = idx >> 3, c = idx & 7;
                    char* baseB = (char*)Bs + (size_t)(it * 256 + (tid & ~63)) * 16;
                    gll16(Bb + (size_t)(mt * 128 + brow) * 1024 + ks * 64 + (c ^ (brow & 7)) * 8,
                          baseB);
                }
            }
            __syncthreads();

            const char* xb = (const char*)Xs + (wr * 64 + l15) * 128;
            const char* bb = (const char*)Bs + (wc * 64 + l15) * 128;
            const int sw = (l15 & 7) << 4;
#pragma unroll
            for (int kk = 0; kk < 2; ++kk) {
                const int ob = (kk * 64 + lg * 16) ^ sw;
                bf16x8 a[4], bq[4];
#pragma unroll
                for (int mi = 0; mi < 4; ++mi) a[mi] = *(const bf16x8*)(xb + mi * 2048 + ob);
#pragma unroll
                for (int ni = 0; ni < 4; ++ni) bq[ni] = *(const bf16x8*)(bb + ni * 2048 + ob);
#pragma unroll
                for (int mi = 0; mi < 4; ++mi)
#pragma unroll
                    for (int ni = 0; ni < 4; ++ni)
                        acc[mi][ni] = __builtin_amdgcn_mfma_f32_16x16x32_bf16(
                            a[mi], bq[ni], acc[mi][ni], 0, 0, 0);
            }
        }
#pragma unroll
        for (int mi = 0; mi < 4; ++mi)
#pragma unroll
            for (int ni = 0; ni < 4; ++ni)
#pragma unroll
                for (int r = 0; r < 4; ++r)
                    nsq_reg[mi][r] += acc[mi][ni][r] * acc[mi][ni][r];
    }

    if (tid < 128) nsq_s[tid] = 0.f;
    __syncthreads();
#pragma unroll
    for (int mi = 0; mi < 4; ++mi)
#pragma unroll
        for (int r = 0; r < 4; ++r) {
            float v = nsq_reg[mi][r];
            v += __shfl_xor(v, 1);
            v += __shfl_xor(v, 2);
            v += __shfl_xor(v, 4);
            v += __shfl_xor(v, 8);
            if (l15 == 0) atomicAdd(&nsq_s[wr * 64 + mi * 16 + lg * 4 + r], v);
        }
    __syncthreads();
    if (tid < 128) nsq_g[(size_t)mh * 65536 + st + tid] = nsq_s[tid];
}

// ---- fallback pass 4 ----
__global__ __launch_bounds__(256, 2) void k_finish0(
    const float* __restrict__ x, const float* __restrict__ w,
    const float* __restrict__ nsq_g, float* __restrict__ outp,
    float* __restrict__ sim_out) {
    __shared__ __align__(16) unsigned short xt[32 * 1024];
    __shared__ float numer[32];
    __shared__ float simv[32];

    const int tid = threadIdx.x;
    const int bs = blockIdx.x;
    const int b = bs >> 7, s0 = (bs & 127) * 32;
    const size_t tok0 = (size_t)b * 4096 + s0;

    const float4* src = (const float4*)(x + tok0 * 1024) + tid;
    char* lds = (char*)xt;
    for (int r = 0; r < 32; ++r) {
        float4 v = src[r * 256];
        uint2 p;
        p.x = f2bf(v.x) | (f2bf(v.y) << 16);
        p.y = f2bf(v.z) | (f2bf(v.w) << 16);
        *(uint2*)(lds + r * 2048 + ((tid * 8) ^ ((r & 7) << 4))) = p;
    }
    __syncthreads();

    {
        const int t = tid >> 3, kp = tid & 7;
        const float* wb = w + (size_t)b * 1024 + kp * 128;
        const char* pt = (const char*)xt + t * 2048;
        const int sw2 = (t & 7) << 4;
        float acc = 0.f;
#pragma unroll
        for (int j = 0; j < 16; ++j) {
            const int kb = (kp * 128 + j * 8) * 2;
            bf16x8 v = *(const bf16x8*)(pt + (kb ^ sw2));
#pragma unroll
            for (int e = 0; e < 8; ++e) acc += (float)v[e] * wb[j * 8 + e];
        }
        acc += __shfl_xor(acc, 1);
        acc += __shfl_xor(acc, 2);
        acc += __shfl_xor(acc, 4);
        if (kp == 0) numer[t] = acc;
    }
    __syncthreads();

    if (tid < 32) {
        float nt = nsq_g[tok0 + tid] + nsq_g[65536 + tok0 + tid];
        float s = numer[tid] / (EPS + sqrtf(nt));
        simv[tid] = s;
        sim_out[tok0 + tid] = s;
    }
    __syncthreads();

    {
        const int n0 = tid * 4;
        float a0 = 0.f, a1 = 0.f, a2 = 0.f, a3 = 0.f;
        const char* p = (const char*)xt;
#pragma unroll 4
        for (int t = 0; t < 32; ++t) {
            int byte = t * 2048 + ((n0 * 2) ^ ((t & 7) << 4));
            bf16x4 v = *(const bf16x4*)(p + byte);
            float s = simv[t];
            a0 += s * (float)v[0];
            a1 += s * (float)v[1];
            a2 += s * (float)v[2];
            a3 += s * (float)v[3];
        }
        float4 o; o.x = a0; o.y = a1; o.z = a2; o.w = a3;
        ((float4*)(outp + (size_t)bs * 1024))[tid] = o;
    }
}

// ---- out[b][j] = sum over NT tile partials ----
template <int NT>
__global__ void k_outred(const float* __restrict__ outp, float* __restrict__ out) {
    const int b = blockIdx.y, j = blockIdx.x * 256 + threadIdx.x;
    const float* p = outp + (size_t)b * NT * 1024 + j;
    float s = 0.f;
    for (int t = 0; t < NT; ++t) s += p[t * 1024];
    out[b * 1024 + j] = s;
}

extern "C" void kernel_launch(void* const* d_in, const int* in_sizes, int n_in,
                              void* d_out, int out_size, void* d_ws, size_t ws_size,
                              hipStream_t stream) {
    const float* x = (const float*)d_in[0];  // [16][4096][1024]
    const float* A = (const float*)d_in[1];  // [1024][1024]
    const float* B = (const float*)d_in[2];  // [1024][1024]
    float* out = (float*)d_out;              // [16][1024] then sim [16][4096]
    float* sim = out + 16 * 1024;
    float* ws = (float*)d_ws;
    float* xs_part = ws;                                  // 524288  (2 MB)
    float* q = ws + 540672;                               // 16384
    float* wv = ws + 557056;                              // 16384
    float* nsq = ws + 573440;                             // 131072 (fallback only)
    float* outp = ws + 704512;                            // up to 8 MB
    unsigned short* Bb = (unsigned short*)(ws + 2801664); // 1M bf16 (2 MB)
    unsigned short* xbf = (unsigned short*)(ws + 3325952);// 64M bf16 (128 MB, optional)
    const bool xb = ws_size >= (size_t)(3325952 + 33554432) * 4;

    if (xb) k_prep<1><<<dim3(32, 16), 256, 0, stream>>>(x, xs_part, xbf);
    else    k_prep<0><<<dim3(32, 16), 256, 0, stream>>>(x, xs_part, (unsigned short*)0);
    k_bconv<<<1024, 256, 0, stream>>>(B, Bb);
    k_queryf<<<dim3(4, 16), 256, 0, stream>>>(xs_part, A, q);
    k_wf<<<dim3(4, 16), 256, 0, stream>>>(B, q, wv);
    if (xb) {
        k_main2<<<256, 512, 0, stream>>>(xbf, Bb, wv, outp, sim);
        k_outred<16><<<dim3(4, 16), 256, 0, stream>>>(outp, out);
    } else {
        k_nsq_f32<<<dim3(512, 2), 256, 0, stream>>>(x, Bb, nsq);
        k_finish0<<<2048, 256, 0, stream>>>(x, wv, nsq, outp, sim);
        k_outred<128><<<dim3(4, 16), 256, 0, stream>>>(outp, out);
    }
}